// Round 8
// baseline (227.587 us; speedup 1.0000x reference)
//
#include <hip/hip_runtime.h>
#include <hip/hip_cooperative_groups.h>
#include <math.h>

namespace cg = cooperative_groups;

// Problem constants (from reference): B=2, L=1024, D=256, P=32
#define B_ 2
#define L_ 1024
#define D_ 256
#define P_ 32
#define NROW (B_*L_)          // 2048 flattened (b,l) rows
#define SEG_ 8                // scan segments per (b,p)
#define SL_ (L_/SEG_)         // 128 positions per segment
#define PIF 3.14159265358979323846f

typedef float nvf2 __attribute__((ext_vector_type(2)));

// ---------------------------------------------------------------------------
// ONE cooperative kernel, 512 blocks x 256 threads (2 blocks/CU guaranteed by
// __launch_bounds__(256,2); LDS 20KB). Three phases with grid-wide syncs:
//  P0: block owns x-rows [4*blk, 4*blk+4): values GEMM (K-split: quarter-wave
//      q covers k in [64q,64q+64), Wv streamed once/block, LDS reduce) and
//      phase GEMM for the SAME rows (tid<128: rr=tid>>5, p=tid&31) -> phases,
//      phasors (d_out) and transposed phasorT[(b*P+p)*L+l] (ws).
//  P1: block = (b,p,seg j); phasors for its 128-l segment cached in LDS;
//      partial S2[(b,p,j),d] = sum_l phasor*v (thread owns dim d=tid).
//  P2: carry = sum of S2 over jj<j (<=7 loads), then 128-step running sum,
//      NT float2 stores (write-once 134MB stream, bypass L2).
// pc stays in LDS across P1->P2 (block-local, no reload).
// ---------------------------------------------------------------------------
__global__ __launch_bounds__(256, 2) void k_fused(
    const float* __restrict__ x, const float* __restrict__ Wp,
    const float* __restrict__ bp, const float* __restrict__ Wv,
    const float* __restrict__ bv, float* __restrict__ values,
    float* __restrict__ phases_out, float* __restrict__ phasor_out,
    float2* __restrict__ phasorT, float2* __restrict__ S2,
    float* __restrict__ mem, int mode, int phasorMode)
{
    cg::grid_group grid = cg::this_grid();
    __shared__ float smem[5120];                 // 20 KB
    const int tid = threadIdx.x;
    const int blk = blockIdx.x;

    // ---------------- PHASE 0: projections ----------------
    {
        const int row0 = blk * 4;
        float*  xsv = smem;                      // 4 rows x 256 = 4 KB
        float4* red = (float4*)(smem + 1024);    // 16 KB reduce buffer

        ((float4*)xsv)[tid] = ((const float4*)(x + (size_t)row0 * D_))[tid];
        __syncthreads();

        const int q  = tid >> 6;                 // k-quarter (wave-uniform)
        const int c4 = tid & 63;
        const float4* Wv4 = (const float4*)Wv;
        float4 acc[4];
        #pragma unroll
        for (int r = 0; r < 4; ++r) acc[r] = make_float4(0.f, 0.f, 0.f, 0.f);
        const int k0 = q * 64;
        #pragma unroll 4
        for (int kk = 0; kk < 64; ++kk) {
            const int k = k0 + kk;
            float4 w = Wv4[k * 64 + c4];         // coalesced, Wv once/block
            #pragma unroll
            for (int r = 0; r < 4; ++r) {
                float xv = xsv[r * D_ + k];      // wave-uniform LDS broadcast
                acc[r].x += xv * w.x; acc[r].y += xv * w.y;
                acc[r].z += xv * w.z; acc[r].w += xv * w.w;
            }
        }
        #pragma unroll
        for (int r = 0; r < 4; ++r) red[(r * 4 + q) * 64 + c4] = acc[r];
        __syncthreads();

        const int r2 = tid >> 6;
        float4 s0 = red[(r2 * 4 + 0) * 64 + c4];
        float4 s1 = red[(r2 * 4 + 1) * 64 + c4];
        float4 s2 = red[(r2 * 4 + 2) * 64 + c4];
        float4 s3 = red[(r2 * 4 + 3) * 64 + c4];
        const float4 b4 = ((const float4*)bv)[c4];
        float4 vo;
        vo.x = s0.x + s1.x + s2.x + s3.x + b4.x;
        vo.y = s0.y + s1.y + s2.y + s3.y + b4.y;
        vo.z = s0.z + s1.z + s2.z + s3.z + b4.z;
        vo.w = s0.w + s1.w + s2.w + s3.w + b4.w;
        ((float4*)values)[(size_t)(row0 + r2) * 64 + c4] = vo;

        // phase GEMM for the same 4 rows (xsv still intact)
        if (tid < 4 * P_) {
            const int rr = tid >> 5;             // 0..3
            const int p  = tid & (P_ - 1);
            const float* xr = xsv + rr * D_;
            float a = 0.f;
            #pragma unroll 8
            for (int k = 0; k < D_; ++k)
                a += xr[k] * Wp[k * P_ + p];
            float ph = tanhf(a + bp[p]) * PIF;
            const int row = row0 + rr;
            const int idx = row * P_ + p;
            phases_out[idx] = ph;
            float s, c;
            sincosf(ph, &s, &c);
            if (phasorMode == 0)      ((float2*)phasor_out)[idx] = make_float2(c, s);
            else if (phasorMode == 1) phasor_out[idx] = c;
            const int b = row >> 10, l = row & (L_ - 1);
            phasorT[(b * P_ + p) * L_ + l] = make_float2(c, s);
        }
    }
    grid.sync();

    // block -> (b, p, segment j)
    const int b  = blk >> 8;
    const int p  = (blk >> 3) & (P_ - 1);
    const int j  = blk & (SEG_ - 1);
    const int l0 = j * SL_;

    float2* pc = (float2*)smem;                  // 128 float2 = 1 KB (reuse)
    if (tid < SL_) pc[tid] = phasorT[(b * P_ + p) * L_ + l0 + tid];
    __syncthreads();

    // ---------------- PHASE 1: segment partials ----------------
    const float* vbase = values + (size_t)(b * L_ + l0) * D_ + tid;
    float2 accp = make_float2(0.f, 0.f);
    #pragma unroll 8
    for (int i = 0; i < SL_; ++i) {
        float  v  = vbase[i * D_];               // 4B/lane coalesced (L2)
        float2 cs = pc[i];                       // same-addr LDS broadcast
        accp.x += cs.x * v;
        accp.y += cs.y * v;
    }
    S2[((b * P_ + p) * SEG_ + j) * D_ + tid] = accp;
    grid.sync();

    // ---------------- PHASE 2: scan with carry ----------------
    float2 carry = make_float2(0.f, 0.f);
    const float2* Sb = S2 + (size_t)(b * P_ + p) * SEG_ * D_ + tid;
    for (int jj = 0; jj < j; ++jj) {             // <=7 independent loads
        float2 s = Sb[jj * D_];
        carry.x += s.x; carry.y += s.y;
    }
    #pragma unroll 4
    for (int i = 0; i < SL_; ++i) {
        float  v  = vbase[i * D_];
        float2 cs = pc[i];
        carry.x += cs.x * v;
        carry.y += cs.y * v;
        const size_t rowIdx = (size_t)(b * L_ + l0 + i) * P_ + p;
        if (mode == 0) {
            nvf2 cv = { carry.x, carry.y };
            __builtin_nontemporal_store(cv, (nvf2*)mem + rowIdx * D_ + tid);
        } else {
            __builtin_nontemporal_store(carry.x, mem + rowIdx * D_ + tid);
        }
    }
}

// ---------------------------------------------------------------------------
// Parachute (non-cooperative, small-ws): round-6 proj + carry-recompute scan.
// Only used if ws can't hold values+phasorT+S2 (never observed).
// ---------------------------------------------------------------------------
__global__ __launch_bounds__(256) void k_proj_pc(
    const float* __restrict__ x, const float* __restrict__ Wp,
    const float* __restrict__ bp, const float* __restrict__ Wv,
    const float* __restrict__ bv, float* __restrict__ values,
    float* __restrict__ phases_out, float* __restrict__ phasor_out,
    int phasorMode)
{
    __shared__ float xs[8 * D_];
    const int tid = threadIdx.x;
    if (blockIdx.x < NROW / 4) {
        const int row0 = blockIdx.x * 4;
        ((float4*)xs)[tid] = ((const float4*)(x + (size_t)row0 * D_))[tid];
        __syncthreads();
        const int c4 = tid & 63, r = tid >> 6;
        const float* xr = xs + r * D_;
        const float4* Wv4 = (const float4*)Wv;
        float4 acc = make_float4(0.f, 0.f, 0.f, 0.f);
        for (int k = 0; k < D_; ++k) {
            float4 w = Wv4[k * 64 + c4];
            float xv = xr[k];
            acc.x += xv * w.x; acc.y += xv * w.y;
            acc.z += xv * w.z; acc.w += xv * w.w;
        }
        const float4 b4 = ((const float4*)bv)[c4];
        acc.x += b4.x; acc.y += b4.y; acc.z += b4.z; acc.w += b4.w;
        ((float4*)values)[(size_t)(row0 + r) * 64 + c4] = acc;
    } else {
        const int row0 = (blockIdx.x - NROW / 4) * 8;
        const float4* xg4 = (const float4*)(x + (size_t)row0 * D_);
        ((float4*)xs)[tid]       = xg4[tid];
        ((float4*)xs)[tid + 256] = xg4[tid + 256];
        __syncthreads();
        const int p = tid & (P_ - 1), rr = tid >> 5;
        const float* xr = xs + rr * D_;
        float a = 0.f;
        for (int k = 0; k < D_; ++k) a += xr[k] * Wp[k * P_ + p];
        float ph = tanhf(a + bp[p]) * PIF;
        const int idx = (row0 + rr) * P_ + p;
        phases_out[idx] = ph;
        float s, c;
        sincosf(ph, &s, &c);
        if (phasorMode == 0)      ((float2*)phasor_out)[idx] = make_float2(c, s);
        else if (phasorMode == 1) phasor_out[idx] = c;
    }
}

__global__ __launch_bounds__(128) void k_scan_rc(
    const float* __restrict__ values, const float* __restrict__ phases,
    float* __restrict__ mem, int mode)
{
    const int blk = blockIdx.x;
    const int c = blk & 15, p = (blk >> 4) & (P_ - 1), b = blk >> 9;
    const int tid = threadIdx.x;
    const int l0 = c * 64;
    const float2* vb = (const float2*)(values + (size_t)b * L_ * D_);
    float4 carry = make_float4(0.f, 0.f, 0.f, 0.f);
    for (int l = 0; l < l0 + 64; ++l) {
        float ph = phases[(b * L_ + l) * P_ + p];
        float s = __sinf(ph), cs = __cosf(ph);
        float2 v = vb[l * (D_/2) + tid];
        carry.x += cs * v.x; carry.y += s * v.x;
        carry.z += cs * v.y; carry.w += s * v.y;
        if (l >= l0) {
            const size_t rowIdx = (size_t)(b * L_ + l) * P_ + p;
            if (mode == 0) ((float4*)mem)[rowIdx * (D_/2) + tid] = carry;
            else ((float2*)mem)[rowIdx * (D_/2) + tid] = make_float2(carry.x, carry.z);
        }
    }
}

extern "C" void kernel_launch(void* const* d_in, const int* in_sizes, int n_in,
                              void* d_out, int out_size, void* d_ws, size_t ws_size,
                              hipStream_t stream) {
    const float* x  = (const float*)d_in[0];
    const float* Wp = (const float*)d_in[1];
    const float* bp = (const float*)d_in[2];
    const float* Wv = (const float*)d_in[3];
    const float* bv = (const float*)d_in[4];
    float* out = (float*)d_out;

    const size_t nMemF = (size_t)2 * B_ * L_ * P_ * D_;  // 33554432 (interleaved)
    const size_t nMemR = (size_t)B_ * L_ * P_ * D_;      // 16777216 (real only)
    const size_t nPh   = (size_t)B_ * L_ * P_;           // 65536

    // Output layout mode by out_size (rounds 3-7 verified: mode 0 —
    // memory interleaved complex | phases | phasors interleaved).
    int mode; size_t memFloats;
    if ((size_t)out_size >= nMemF + 3 * nPh) { mode = 0; memFloats = nMemF; }
    else                                     { mode = 1; memFloats = nMemR; }
    const bool memFits      = (size_t)out_size >= memFloats;
    const bool phasesInOut  = (size_t)out_size >= memFloats + nPh;
    const bool phasorsInOut =
        (size_t)out_size >= memFloats + nPh + (mode == 0 ? 2 * nPh : nPh);

    // ws layout: values | phasorT | S2 | phasesWs
    const size_t valB = (size_t)B_ * L_ * D_ * sizeof(float);            // 2 MB
    const size_t ptB  = (size_t)B_ * P_ * L_ * sizeof(float2);           // 512 KB
    const size_t s2B  = (size_t)B_ * P_ * SEG_ * D_ * sizeof(float2);    // 1 MB
    const size_t phB  = nPh * sizeof(float);                             // 256 KB
    float*  values  = (float*)d_ws;
    float2* phasorT = (float2*)((char*)d_ws + valB);
    float2* S2      = (float2*)((char*)d_ws + valB + ptB);
    float*  phasesWs = (float*)((char*)d_ws + valB + ptB + s2B);

    float* phasesPtr = phasesInOut ? (out + memFloats)
                     : (ws_size >= valB + ptB + s2B + phB ? phasesWs
                     : (ws_size >= phB ? (float*)d_ws : nullptr));
    if (phasesPtr == nullptr || !memFits) return;   // unreachable in practice

    float* phasorPtr = phasorsInOut ? (out + memFloats + nPh) : nullptr;
    const int phasorMode = phasorsInOut ? mode : 2;

    if (ws_size >= valB + ptB + s2B) {
        // Primary: single cooperative fused kernel
        void* args[] = {
            (void*)&x, (void*)&Wp, (void*)&bp, (void*)&Wv, (void*)&bv,
            (void*)&values, (void*)&phasesPtr, (void*)&phasorPtr,
            (void*)&phasorT, (void*)&S2, (void*)&out,
            (void*)&mode, (void*)&phasorMode
        };
        hipLaunchCooperativeKernel((void*)k_fused, dim3(NROW / 4), dim3(256),
                                   args, 0, stream);
    } else {
        // Parachute: 2-kernel non-cooperative path
        k_proj_pc<<<NROW / 4 + NROW / 8, 256, 0, stream>>>(
            x, Wp, bp, Wv, bv, values, phasesPtr, phasorPtr, phasorMode);
        k_scan_rc<<<B_ * P_ * 16, 128, 0, stream>>>(values, phasesPtr, out, mode);
    }
}